// Round 1
// baseline (267.457 us; speedup 1.0000x reference)
//
#include <hip/hip_runtime.h>

#define BROWS 131072
#define MDIM 64
#define NDIM 121
#define STAGES 9

// ws layout (floats):
//   [0,     4096)  R    (64x64)
//   [4096, 11840)  PhiT (121x64)
//   [12288, 20032) GT   (121x64)   GT[n][k] = (F_9 * Phi)[k][n]

// ---------------------------------------------------------------- kernel A
// R = Phi * Phi^T (64x64, symmetric) and PhiT (121x64 transpose of Phi).
__global__ void prep_kernel(const float* __restrict__ Phi,
                            float* __restrict__ R,
                            float* __restrict__ PhiT) {
    int id = blockIdx.x * blockDim.x + threadIdx.x;
    if (id < MDIM * MDIM) {
        int i = id >> 6, j = id & 63;
        const float* a = Phi + i * NDIM;
        const float* b = Phi + j * NDIM;
        float s0 = 0.f, s1 = 0.f, s2 = 0.f, s3 = 0.f;
        for (int n = 0; n < 120; n += 4) {
            s0 += a[n + 0] * b[n + 0];
            s1 += a[n + 1] * b[n + 1];
            s2 += a[n + 2] * b[n + 2];
            s3 += a[n + 3] * b[n + 3];
        }
        R[id] = (s0 + s1) + (s2 + s3) + a[120] * b[120];
    }
    int id2 = id - MDIM * MDIM;
    if (id2 >= 0 && id2 < NDIM * MDIM) {
        int n = id2 >> 6, k = id2 & 63;
        PhiT[id2] = Phi[k * NDIM + n];
    }
}

// ---------------------------------------------------------------- kernel B
// F-recurrence engine: one block, 4 waves. lane i holds F row i in VGPRs.
// Wave w owns output columns j in [16w, 16w+16). R rows are wave-uniform
// loads (scalarizable). F column-slices exchanged via padded LDS [64][65].
__global__ __launch_bounds__(256) void fmat_kernel(const float* __restrict__ R,
                                                   const float* __restrict__ PhiT,
                                                   const float* __restrict__ gammas,
                                                   float* __restrict__ GT) {
    __shared__ float sF[MDIM * 65];
    const int tid = threadIdx.x;
    const int lane = tid & 63;
    const int wave = tid >> 6;
    const int jbase = wave * 16;

    float f[64];
#pragma unroll
    for (int m = 0; m < 64; ++m) f[m] = (lane == m) ? 1.0f : 0.0f;
    for (int u = 0; u < 16; ++u) {
        int j = jbase + u;
        sF[lane * 65 + j] = (lane == j) ? 1.0f : 0.0f;
    }
    __syncthreads();

    for (int s = 0; s < STAGES; ++s) {
        float gam = gammas[s];
        for (int u = 0; u < 16; ++u) {
            int j = jbase + u;
            const float4* Rr = (const float4*)(R + j * 64);  // uniform address
            float ax = 0.f, ay = 0.f, az = 0.f, aw = 0.f;
#pragma unroll
            for (int q = 0; q < 16; ++q) {
                float4 rv = Rr[q];
                ax += f[4 * q + 0] * rv.x;
                ay += f[4 * q + 1] * rv.y;
                az += f[4 * q + 2] * rv.z;
                aw += f[4 * q + 3] * rv.w;
            }
            float mij = (ax + ay) + (az + aw);      // (F R)[i][j], R symmetric
            float rjj = R[j * 64 + j];
            float d = 1.0f / (rjj + gam);
            float fold = sF[lane * 65 + j];
            float del = (lane == j) ? 1.0f : 0.0f;
            sF[lane * 65 + j] = fold + d * (del - mij);   // F_{s+1}[i][j]
        }
        __syncthreads();
#pragma unroll
        for (int m = 0; m < 64; ++m) f[m] = sF[lane * 65 + m];  // refill regs
        __syncthreads();
    }

    // GT[n][lane] = sum_m F[lane][m] * PhiT[n][m]
    for (int n = wave; n < NDIM; n += 4) {
        const float4* pr = (const float4*)(PhiT + n * 64);  // uniform address
        float ax = 0.f, ay = 0.f, az = 0.f, aw = 0.f;
#pragma unroll
        for (int q = 0; q < 16; ++q) {
            float4 pv = pr[q];
            ax += f[4 * q + 0] * pv.x;
            ay += f[4 * q + 1] * pv.y;
            az += f[4 * q + 2] * pv.z;
            aw += f[4 * q + 3] * pv.w;
        }
        GT[n * 64 + lane] = (ax + ay) + (az + aw);
    }
}

// ---------------------------------------------------------------- kernel C
// theta[r][n] = sum_k y[r][k] * GT[n][k]. Thread-per-row, y row in 64 VGPRs,
// GT rows wave-uniform-loaded. Stores staged through LDS for coalescing
// (row stride 484B is 4 mod 16 -> no aligned vector stores possible).
__global__ __launch_bounds__(256, 2) void gemm_kernel(const float* __restrict__ y,
                                                      const float* __restrict__ GT,
                                                      float* __restrict__ out) {
    __shared__ float so[256 * 17];
    const int tid = threadIdx.x;
    const long long row0 = (long long)blockIdx.x * 256;
    const long long row = row0 + tid;

    float yv[64];
    {
        const float4* yr = (const float4*)(y + row * 64);
#pragma unroll
        for (int q = 0; q < 16; ++q) {
            float4 t = yr[q];
            yv[4 * q + 0] = t.x;
            yv[4 * q + 1] = t.y;
            yv[4 * q + 2] = t.z;
            yv[4 * q + 3] = t.w;
        }
    }

    for (int nc = 0; nc < 8; ++nc) {
        const int n0 = nc * 16;
        const int cc = (nc == 7) ? 9 : 16;
        for (int u = 0; u < cc; ++u) {
            const float4* gr = (const float4*)(GT + (n0 + u) * 64);  // uniform
            float ax = 0.f, ay = 0.f, az = 0.f, aw = 0.f;
#pragma unroll
            for (int q = 0; q < 16; ++q) {
                float4 g = gr[q];
                ax += yv[4 * q + 0] * g.x;
                ay += yv[4 * q + 1] * g.y;
                az += yv[4 * q + 2] * g.z;
                aw += yv[4 * q + 3] * g.w;
            }
            so[tid * 17 + u] = (ax + ay) + (az + aw);
        }
        __syncthreads();
        {
            const int col = tid & 15;
            const int rbase = tid >> 4;
            if (col < cc) {
#pragma unroll
                for (int rep = 0; rep < 16; ++rep) {
                    int rl = rep * 16 + rbase;
                    out[(row0 + rl) * NDIM + n0 + col] = so[rl * 17 + col];
                }
            }
        }
        __syncthreads();
    }
}

extern "C" void kernel_launch(void* const* d_in, const int* in_sizes, int n_in,
                              void* d_out, int out_size, void* d_ws, size_t ws_size,
                              hipStream_t stream) {
    const float* y      = (const float*)d_in[0];
    const float* Phi    = (const float*)d_in[1];
    const float* gammas = (const float*)d_in[2];
    float* out = (float*)d_out;

    float* R    = (float*)d_ws;
    float* PhiT = R + 4096;
    float* GT   = R + 12288;

    prep_kernel<<<(MDIM * MDIM + NDIM * MDIM + 255) / 256, 256, 0, stream>>>(Phi, R, PhiT);
    fmat_kernel<<<1, 256, 0, stream>>>(R, PhiT, gammas, GT);
    gemm_kernel<<<BROWS / 256, 256, 0, stream>>>(y, GT, out);
}